// Round 1
// baseline (326.422 us; speedup 1.0000x reference)
//
#include <hip/hip_runtime.h>
#include <math.h>

#define BB 4
#define NN 8192
#define LL 512
#define NSUB 1024
#define TILE 256
#define NSLICE 4
#define SLICE_LEN (NN / NSLICE)

// ws layout (floats):
// [0..15]  accumulators: 0=chamfer min-sum, 1=kl sum, 2=sizing sum, 3=material sum,
//          4..7 = density sum per batch, 8..11 = density sumsq per batch
// [16 .. 16 + 2*BB*NN) = per-point min array (dir, b, n), init +inf
#define ACC_N 16
#define MINARR_LEN (2 * BB * NN)

__device__ inline float blockReduceSum256(float v) {
    __shared__ float red[4];
    #pragma unroll
    for (int o = 32; o; o >>= 1) v += __shfl_down(v, o);
    __syncthreads();
    if ((threadIdx.x & 63) == 0) red[threadIdx.x >> 6] = v;
    __syncthreads();
    return red[0] + red[1] + red[2] + red[3];  // valid in all threads
}

__global__ void init_ws_kernel(float* ws) {
    int total = ACC_N + MINARR_LEN;
    for (int i = blockIdx.x * blockDim.x + threadIdx.x; i < total;
         i += gridDim.x * blockDim.x) {
        ws[i] = (i < ACC_N) ? 0.0f : __int_as_float(0x7F800000);  // +inf
    }
}

// One thread = one query point (register-resident). Other point set staged
// through LDS in 256-point float4 tiles. blockIdx: x=chunk(32), y=slice(4),
// z = b*2 + dir. dir0: query=pred, other=target (min over m). dir1 swapped.
__global__ __launch_bounds__(256) void chamfer_kernel(
    const float* __restrict__ pred, const float* __restrict__ targ,
    float* __restrict__ ws) {
    __shared__ float4 tile[TILE];
    const int tid = threadIdx.x;
    const int chunk = blockIdx.x;
    const int slice = blockIdx.y;
    const int b = blockIdx.z >> 1;
    const int dir = blockIdx.z & 1;
    const float* __restrict__ P = dir ? targ : pred;
    const float* __restrict__ T = dir ? pred : targ;

    const int n = chunk * TILE + tid;
    const float* pp = P + ((size_t)b * NN + n) * 3;
    const float px = pp[0], py = pp[1], pz = pp[2];

    float m = __int_as_float(0x7F800000);
    const int tbase = slice * SLICE_LEN;
    for (int t0 = 0; t0 < SLICE_LEN; t0 += TILE) {
        __syncthreads();
        const float* tp = T + ((size_t)b * NN + tbase + t0 + tid) * 3;
        tile[tid] = make_float4(tp[0], tp[1], tp[2], 0.0f);
        __syncthreads();
        #pragma unroll 8
        for (int j = 0; j < TILE; ++j) {
            float4 q = tile[j];
            float dx = px - q.x, dy = py - q.y, dz = pz - q.z;
            float d = fmaf(dx, dx, fmaf(dy, dy, dz * dz));
            m = fminf(m, d);
        }
    }
    // d >= 0 always -> int compare == float compare
    int* dst = (int*)&ws[ACC_N + (size_t)dir * BB * NN + (size_t)b * NN + n];
    atomicMin(dst, __float_as_int(m));
}

__global__ void reduce_min_sum_kernel(const float* __restrict__ ws_ro,
                                      float* __restrict__ ws) {
    float s = 0.0f;
    for (int i = blockIdx.x * blockDim.x + threadIdx.x; i < MINARR_LEN;
         i += gridDim.x * blockDim.x)
        s += ws_ro[ACC_N + i];
    s = blockReduceSum256(s);
    if (threadIdx.x == 0) atomicAdd(&ws[0], s);
}

// KL + sizing + material in one pass (three grid-stride segments)
__global__ void small_losses_kernel(const float* __restrict__ mu,
                                    const float* __restrict__ logvar,
                                    const float* __restrict__ pred_siz,
                                    const float* __restrict__ targ_siz,
                                    const float* __restrict__ pred_mat,
                                    const float* __restrict__ targ_mat,
                                    float* __restrict__ ws) {
    const int stride = gridDim.x * blockDim.x;
    const int t0 = blockIdx.x * blockDim.x + threadIdx.x;

    float skl = 0.0f;
    for (int i = t0; i < BB * LL; i += stride) {
        float m = mu[i], lv = logvar[i];
        skl += 1.0f + lv - m * m - expf(lv);
    }
    float ssz = 0.0f;
    for (int i = t0; i < BB * NN; i += stride) {
        float d = pred_siz[i] - targ_siz[i];
        ssz = fmaf(d, d, ssz);
    }
    float smt = 0.0f;
    for (int i = t0; i < BB * NN * 4; i += stride) {
        float d = pred_mat[i] - targ_mat[i];
        smt = fmaf(d, d, smt);
    }
    skl = blockReduceSum256(skl);
    __syncthreads();
    ssz = blockReduceSum256(ssz);
    __syncthreads();
    smt = blockReduceSum256(smt);
    if (threadIdx.x == 0) {
        atomicAdd(&ws[1], skl);
        atomicAdd(&ws[2], ssz);
        atomicAdd(&ws[3], smt);
    }
}

// density: pts = pred_pos[b, sub_idx]; nn_d = min_{j!=diag} ||pi-pj||^2 with
// +1e6 on the diagonal (exactly as reference). blockIdx.x=chunk(4), y=b.
__global__ __launch_bounds__(256) void density_kernel(
    const float* __restrict__ pred, const int* __restrict__ sub_idx,
    float* __restrict__ ws) {
    __shared__ float4 pts[NSUB];  // 16 KiB
    const int tid = threadIdx.x;
    const int chunk = blockIdx.x;
    const int b = blockIdx.y;
    for (int k = tid; k < NSUB; k += 256) {
        int idx = sub_idx[k];
        const float* p = pred + ((size_t)b * NN + idx) * 3;
        pts[k] = make_float4(p[0], p[1], p[2], 0.0f);
    }
    __syncthreads();
    const int i = chunk * 256 + tid;
    const float4 me = pts[i];
    float m = __int_as_float(0x7F800000);
    for (int j = 0; j < NSUB; ++j) {
        float4 q = pts[j];
        float dx = me.x - q.x, dy = me.y - q.y, dz = me.z - q.z;
        float d = fmaf(dx, dx, fmaf(dy, dy, dz * dz));
        d += (j == i) ? 1.0e6f : 0.0f;
        m = fminf(m, d);
    }
    float s = blockReduceSum256(m);
    __syncthreads();
    float ss = blockReduceSum256(m * m);
    if (tid == 0) {
        atomicAdd(&ws[4 + b], s);
        atomicAdd(&ws[8 + b], ss);
    }
}

__global__ void finalize_kernel(const float* __restrict__ ws,
                                float* __restrict__ out) {
    if (threadIdx.x != 0 || blockIdx.x != 0) return;
    float cd = ws[0] / (float)(BB * NN);
    float kl = -0.5f * ws[1] / (float)(BB * LL);
    float sizing = ws[2] / (float)(BB * NN);
    float material = ws[3] / (float)(BB * NN * 4);
    float den = 0.0f;
    for (int b = 0; b < BB; ++b) {
        float s = ws[4 + b], ss = ws[8 + b];
        float var = (ss - s * s / (float)NSUB) / (float)(NSUB - 1);
        den += sqrtf(fmaxf(var, 0.0f));
    }
    den *= (1.0f / BB);
    out[0] = cd + 0.001f * kl + 0.1f * den + 0.05f * sizing + 0.1f * material;
}

extern "C" void kernel_launch(void* const* d_in, const int* in_sizes, int n_in,
                              void* d_out, int out_size, void* d_ws,
                              size_t ws_size, hipStream_t stream) {
    const float* pred_pos = (const float*)d_in[0];
    const float* pred_siz = (const float*)d_in[1];
    const float* pred_mat = (const float*)d_in[2];
    const float* targ_pos = (const float*)d_in[3];
    const float* targ_siz = (const float*)d_in[4];
    const float* targ_mat = (const float*)d_in[5];
    const float* mu = (const float*)d_in[6];
    const float* logvar = (const float*)d_in[7];
    const int* sub_idx = (const int*)d_in[8];
    float* out = (float*)d_out;
    float* ws = (float*)d_ws;

    init_ws_kernel<<<64, 256, 0, stream>>>(ws);
    chamfer_kernel<<<dim3(NN / TILE, NSLICE, BB * 2), 256, 0, stream>>>(
        pred_pos, targ_pos, ws);
    reduce_min_sum_kernel<<<64, 256, 0, stream>>>(ws, ws);
    small_losses_kernel<<<64, 256, 0, stream>>>(mu, logvar, pred_siz, targ_siz,
                                                pred_mat, targ_mat, ws);
    density_kernel<<<dim3(NSUB / 256, BB), 256, 0, stream>>>(pred_pos, sub_idx,
                                                             ws);
    finalize_kernel<<<1, 64, 0, stream>>>(ws, out);
}

// Round 2
// 124.516 us; speedup vs baseline: 2.6215x; 2.6215x over previous
//
#include <hip/hip_runtime.h>
#include <math.h>

#define BB 4
#define NN 8192
#define LL 512
#define NSUB 1024
#define QPT 8                       // query points per thread
#define NSLICE 32
#define SLICE (NN / NSLICE)         // 256 target points per block
#define NCHUNK (NN / (256 * QPT))   // 4

// ws layout:
// float ws[0..15]: 0=chamfer sum, 1=kl, 2=sizing, 3=material,
//                  4..7 density sum/b, 8..11 density sumsq/b
// unsigned umax[2*BB*NN] at ws+16: order-preserving-key max of
//   h = p.q - 0.5|q|^2 per (dir,b,n); init 0 == smallest key
#define ACC_N 16
#define MAXARR_LEN (2 * BB * NN)

// order-preserving float -> uint32 (monotone, handles negatives)
__device__ inline unsigned fkey(float f) {
    unsigned b = __float_as_uint(f);
    return (b & 0x80000000u) ? ~b : (b | 0x80000000u);
}
__device__ inline float fkeyinv(unsigned u) {
    unsigned b = (u & 0x80000000u) ? (u & 0x7FFFFFFFu) : ~u;
    return __uint_as_float(b);
}

__device__ inline float blockReduceSum256(float v) {
    __shared__ float red[4];
    #pragma unroll
    for (int o = 32; o; o >>= 1) v += __shfl_down(v, o);
    __syncthreads();
    if ((threadIdx.x & 63) == 0) red[threadIdx.x >> 6] = v;
    __syncthreads();
    return red[0] + red[1] + red[2] + red[3];
}

__global__ void init_ws_kernel(unsigned* __restrict__ ws) {
    const int total = ACC_N + MAXARR_LEN;
    for (int i = blockIdx.x * blockDim.x + threadIdx.x; i < total;
         i += gridDim.x * blockDim.x)
        ws[i] = 0u;
}

// blockIdx: x=chunk(4), y=slice(32), z=b*2+dir.
// Each thread owns QPT=8 register-resident query points; SLICE=256 target
// points staged in LDS as (x,y,z,-0.5*|q|^2). Inner body: 3 FMA + 1 max.
__global__ __launch_bounds__(256) void chamfer_kernel(
    const float* __restrict__ pred, const float* __restrict__ targ,
    unsigned* __restrict__ umax) {
    __shared__ float4 tile[SLICE];
    const int tid = threadIdx.x;
    const int chunk = blockIdx.x;
    const int slice = blockIdx.y;
    const int b = blockIdx.z >> 1;
    const int dir = blockIdx.z & 1;
    const float* __restrict__ P = dir ? targ : pred;
    const float* __restrict__ T = dir ? pred : targ;

    {   // stage one target point per thread (SLICE == blockDim)
        const float* tp = T + ((size_t)b * NN + slice * SLICE + tid) * 3;
        float x = tp[0], y = tp[1], z = tp[2];
        tile[tid] = make_float4(x, y, z, -0.5f * fmaf(x, x, fmaf(y, y, z * z)));
    }

    float px[QPT], py[QPT], pz[QPT], h[QPT];
    const int qbase = chunk * (256 * QPT) + tid;
    #pragma unroll
    for (int k = 0; k < QPT; ++k) {
        const float* p = P + ((size_t)b * NN + qbase + k * 256) * 3;
        px[k] = p[0]; py[k] = p[1]; pz[k] = p[2];
        h[k] = -1e30f;
    }
    __syncthreads();

    #pragma unroll 4
    for (int j = 0; j < SLICE; ++j) {
        float4 q = tile[j];
        #pragma unroll
        for (int k = 0; k < QPT; ++k) {
            float t = fmaf(pz[k], q.z, q.w);
            t = fmaf(py[k], q.y, t);
            t = fmaf(px[k], q.x, t);
            h[k] = fmaxf(h[k], t);
        }
    }

    unsigned* dst = umax + (size_t)dir * BB * NN + (size_t)b * NN + qbase;
    #pragma unroll
    for (int k = 0; k < QPT; ++k)
        atomicMax(dst + k * 256, fkey(h[k]));
}

// blocks 0..63: chamfer min-sum (recomputes |p|^2) + kl + sizing + material.
// blocks 64..79: density on the 1024-point subsample (chunk = v&3, b = v>>2).
__global__ __launch_bounds__(256) void combined_kernel(
    const float* __restrict__ pred, const float* __restrict__ targ,
    const unsigned* __restrict__ umax,
    const float* __restrict__ mu, const float* __restrict__ logvar,
    const float* __restrict__ psiz, const float* __restrict__ tsiz,
    const float* __restrict__ pmat, const float* __restrict__ tmat,
    const int* __restrict__ sub_idx, float* __restrict__ ws) {
    const int tid = threadIdx.x;
    if (blockIdx.x < 64) {
        const int stride = 64 * 256;
        const int g0 = blockIdx.x * 256 + tid;

        float s = 0.0f;
        for (int i = g0; i < MAXARR_LEN; i += stride) {
            float h = fkeyinv(umax[i]);
            int dir = i >> 15;          // / (BB*NN)
            int r = i & 32767;
            int b = r >> 13;            // / NN
            int n = r & 8191;
            const float* p = (dir ? targ : pred) + ((size_t)b * NN + n) * 3;
            float pp = fmaf(p[0], p[0], fmaf(p[1], p[1], p[2] * p[2]));
            s += pp - 2.0f * h;         // = min squared distance
        }
        float skl = 0.0f;
        for (int i = g0; i < BB * LL; i += stride) {
            float m = mu[i], lv = logvar[i];
            skl += 1.0f + lv - m * m - expf(lv);
        }
        float ssz = 0.0f;
        for (int i = g0; i < BB * NN; i += stride) {
            float d = psiz[i] - tsiz[i];
            ssz = fmaf(d, d, ssz);
        }
        float smt = 0.0f;
        for (int i = g0; i < BB * NN * 4; i += stride) {
            float d = pmat[i] - tmat[i];
            smt = fmaf(d, d, smt);
        }
        s = blockReduceSum256(s);     __syncthreads();
        skl = blockReduceSum256(skl); __syncthreads();
        ssz = blockReduceSum256(ssz); __syncthreads();
        smt = blockReduceSum256(smt);
        if (tid == 0) {
            atomicAdd(&ws[0], s);
            atomicAdd(&ws[1], skl);
            atomicAdd(&ws[2], ssz);
            atomicAdd(&ws[3], smt);
        }
    } else {
        const int v = blockIdx.x - 64;  // 0..15
        const int chunk = v & 3;
        const int b = v >> 2;
        __shared__ float4 pts[NSUB];    // 16 KiB
        for (int k = tid; k < NSUB; k += 256) {
            int idx = sub_idx[k];
            const float* p = pred + ((size_t)b * NN + idx) * 3;
            float x = p[0], y = p[1], z = p[2];
            pts[k] = make_float4(x, y, z, -0.5f * fmaf(x, x, fmaf(y, y, z * z)));
        }
        __syncthreads();
        const int i = chunk * 256 + tid;
        const float4 me = pts[i];
        float h = -1e30f;
        for (int j = 0; j < NSUB; ++j) {
            float4 q = pts[j];
            float t = fmaf(me.z, q.z, q.w);
            t = fmaf(me.y, q.y, t);
            t = fmaf(me.x, q.x, t);
            t = (j == i) ? -1e30f : t;  // exclude diagonal (ref adds 1e6 there)
            h = fmaxf(h, t);
        }
        float pp = fmaf(me.x, me.x, fmaf(me.y, me.y, me.z * me.z));
        float m = pp - 2.0f * h;        // nn squared distance
        float s = blockReduceSum256(m); __syncthreads();
        float ss = blockReduceSum256(m * m);
        if (tid == 0) {
            atomicAdd(&ws[4 + b], s);
            atomicAdd(&ws[8 + b], ss);
        }
    }
}

__global__ void finalize_kernel(const float* __restrict__ ws,
                                float* __restrict__ out) {
    if (threadIdx.x != 0 || blockIdx.x != 0) return;
    float cd = ws[0] / (float)(BB * NN);
    float kl = -0.5f * ws[1] / (float)(BB * LL);
    float sizing = ws[2] / (float)(BB * NN);
    float material = ws[3] / (float)(BB * NN * 4);
    float den = 0.0f;
    for (int b = 0; b < BB; ++b) {
        float s = ws[4 + b], ss = ws[8 + b];
        float var = (ss - s * s / (float)NSUB) / (float)(NSUB - 1);
        den += sqrtf(fmaxf(var, 0.0f));
    }
    den *= (1.0f / BB);
    out[0] = cd + 0.001f * kl + 0.1f * den + 0.05f * sizing + 0.1f * material;
}

extern "C" void kernel_launch(void* const* d_in, const int* in_sizes, int n_in,
                              void* d_out, int out_size, void* d_ws,
                              size_t ws_size, hipStream_t stream) {
    const float* pred_pos = (const float*)d_in[0];
    const float* pred_siz = (const float*)d_in[1];
    const float* pred_mat = (const float*)d_in[2];
    const float* targ_pos = (const float*)d_in[3];
    const float* targ_siz = (const float*)d_in[4];
    const float* targ_mat = (const float*)d_in[5];
    const float* mu = (const float*)d_in[6];
    const float* logvar = (const float*)d_in[7];
    const int* sub_idx = (const int*)d_in[8];
    float* out = (float*)d_out;
    float* ws = (float*)d_ws;
    unsigned* uws = (unsigned*)d_ws;
    unsigned* umax = uws + ACC_N;

    init_ws_kernel<<<64, 256, 0, stream>>>(uws);
    chamfer_kernel<<<dim3(NCHUNK, NSLICE, BB * 2), 256, 0, stream>>>(
        pred_pos, targ_pos, umax);
    combined_kernel<<<80, 256, 0, stream>>>(pred_pos, targ_pos, umax, mu,
                                            logvar, pred_siz, targ_siz,
                                            pred_mat, targ_mat, sub_idx, ws);
    finalize_kernel<<<1, 64, 0, stream>>>(ws, out);
}

// Round 3
// 62.237 us; speedup vs baseline: 5.2448x; 2.0007x over previous
//
#include <hip/hip_runtime.h>
#include <math.h>

#define BB 4
#define NN 8192
#define LL 512
#define NSUB 1024
#define QPT 8                       // query points per thread
#define NSLICE 32
#define SLICE (NN / NSLICE)         // 256 target points per chamfer block
#define NCHUNK (NN / (256 * QPT))   // 4
#define SL_BLOCKS 48                // small-losses blocks in the z=8 slab

// ws layout:
// float ws[0..15]: 0=chamfer sum, 1=kl, 2=sizing, 3=material,
//                  4..7 density sum/b, 8..11 density sumsq/b
// unsigned umax[2*BB*NN] at ws+16: order-preserving-key max of
//   h = p.q - 0.5|q|^2 per (dir,b,n); init 0 == smallest key
#define ACC_N 16
#define MAXARR_LEN (2 * BB * NN)

__device__ inline unsigned fkey(float f) {
    unsigned b = __float_as_uint(f);
    return (b & 0x80000000u) ? ~b : (b | 0x80000000u);
}
__device__ inline float fkeyinv(unsigned u) {
    unsigned b = (u & 0x80000000u) ? (u & 0x7FFFFFFFu) : ~u;
    return __uint_as_float(b);
}

__device__ inline float blockReduceSum256(float v) {
    __shared__ float red[4];
    #pragma unroll
    for (int o = 32; o; o >>= 1) v += __shfl_down(v, o);
    __syncthreads();
    if ((threadIdx.x & 63) == 0) red[threadIdx.x >> 6] = v;
    __syncthreads();
    return red[0] + red[1] + red[2] + red[3];
}

__global__ void init_ws_kernel(unsigned* __restrict__ ws) {
    const int total = ACC_N + MAXARR_LEN;
    for (int i = blockIdx.x * blockDim.x + threadIdx.x; i < total;
         i += gridDim.x * blockDim.x)
        ws[i] = 0u;
}

// grid (4, 32, 9):
//  z in 0..7  -> chamfer: chunk=x, slice=y, b=z>>1, dir=z&1
//  z == 8     -> v = y*4+x: v<16 density (b=v>>2, chunk=v&3);
//                16<=v<64 small-losses (r=v-16 of 48); else idle
__global__ __launch_bounds__(256) void mega_kernel(
    const float* __restrict__ pred, const float* __restrict__ targ,
    unsigned* __restrict__ umax,
    const float* __restrict__ mu, const float* __restrict__ logvar,
    const float* __restrict__ psiz, const float* __restrict__ tsiz,
    const float* __restrict__ pmat, const float* __restrict__ tmat,
    const int* __restrict__ sub_idx, float* __restrict__ ws) {
    __shared__ float4 sh[NSUB];     // chamfer uses [0..255]; density all
    const int tid = threadIdx.x;

    if (blockIdx.z < 8) {           // ---- chamfer ----
        const int chunk = blockIdx.x;
        const int slice = blockIdx.y;
        const int b = blockIdx.z >> 1;
        const int dir = blockIdx.z & 1;
        const float* __restrict__ P = dir ? targ : pred;
        const float* __restrict__ T = dir ? pred : targ;

        {
            const float* tp = T + ((size_t)b * NN + slice * SLICE + tid) * 3;
            float x = tp[0], y = tp[1], z = tp[2];
            sh[tid] = make_float4(x, y, z, -0.5f * fmaf(x, x, fmaf(y, y, z * z)));
        }

        float px[QPT], py[QPT], pz[QPT], h[QPT];
        const int qbase = chunk * (256 * QPT) + tid;
        #pragma unroll
        for (int k = 0; k < QPT; ++k) {
            const float* p = P + ((size_t)b * NN + qbase + k * 256) * 3;
            px[k] = p[0]; py[k] = p[1]; pz[k] = p[2];
            h[k] = -1e30f;
        }
        __syncthreads();

        #pragma unroll 4
        for (int j = 0; j < SLICE; ++j) {
            float4 q = sh[j];
            #pragma unroll
            for (int k = 0; k < QPT; ++k) {
                float t = fmaf(pz[k], q.z, q.w);
                t = fmaf(py[k], q.y, t);
                t = fmaf(px[k], q.x, t);
                h[k] = fmaxf(h[k], t);
            }
        }

        unsigned* dst = umax + (size_t)dir * BB * NN + (size_t)b * NN + qbase;
        #pragma unroll
        for (int k = 0; k < QPT; ++k)
            atomicMax(dst + k * 256, fkey(h[k]));
        return;
    }

    const int v = blockIdx.y * 4 + blockIdx.x;   // 0..127
    if (v < 16) {                   // ---- density ----
        const int chunk = v & 3;
        const int b = v >> 2;
        for (int k = tid; k < NSUB; k += 256) {
            int idx = sub_idx[k];
            const float* p = pred + ((size_t)b * NN + idx) * 3;
            float x = p[0], y = p[1], z = p[2];
            sh[k] = make_float4(x, y, z, -0.5f * fmaf(x, x, fmaf(y, y, z * z)));
        }
        __syncthreads();
        const int i = chunk * 256 + tid;
        const float4 me = sh[i];
        float h0 = -1e30f, h1 = -1e30f, h2 = -1e30f, h3 = -1e30f;
        #pragma unroll 4
        for (int j = 0; j < NSUB; j += 4) {
            float4 q0 = sh[j + 0], q1 = sh[j + 1], q2 = sh[j + 2], q3 = sh[j + 3];
            float t0 = fmaf(me.z, q0.z, q0.w);
            t0 = fmaf(me.y, q0.y, t0); t0 = fmaf(me.x, q0.x, t0);
            t0 = (j + 0 == i) ? -1e30f : t0; h0 = fmaxf(h0, t0);
            float t1 = fmaf(me.z, q1.z, q1.w);
            t1 = fmaf(me.y, q1.y, t1); t1 = fmaf(me.x, q1.x, t1);
            t1 = (j + 1 == i) ? -1e30f : t1; h1 = fmaxf(h1, t1);
            float t2 = fmaf(me.z, q2.z, q2.w);
            t2 = fmaf(me.y, q2.y, t2); t2 = fmaf(me.x, q2.x, t2);
            t2 = (j + 2 == i) ? -1e30f : t2; h2 = fmaxf(h2, t2);
            float t3 = fmaf(me.z, q3.z, q3.w);
            t3 = fmaf(me.y, q3.y, t3); t3 = fmaf(me.x, q3.x, t3);
            t3 = (j + 3 == i) ? -1e30f : t3; h3 = fmaxf(h3, t3);
        }
        float h = fmaxf(fmaxf(h0, h1), fmaxf(h2, h3));
        float pp = fmaf(me.x, me.x, fmaf(me.y, me.y, me.z * me.z));
        float m = pp - 2.0f * h;        // nn squared distance
        float s = blockReduceSum256(m); __syncthreads();
        float ss = blockReduceSum256(m * m);
        if (tid == 0) {
            atomicAdd(&ws[4 + b], s);
            atomicAdd(&ws[8 + b], ss);
        }
    } else if (v < 16 + SL_BLOCKS) {  // ---- kl + sizing + material ----
        const int r = v - 16;
        const int stride = SL_BLOCKS * 256;
        const int g0 = r * 256 + tid;

        float skl = 0.0f;
        for (int i = g0; i < BB * LL; i += stride) {
            float m = mu[i], lv = logvar[i];
            skl += 1.0f + lv - m * m - expf(lv);
        }
        float ssz = 0.0f;
        for (int i = g0; i < BB * NN; i += stride) {
            float d = psiz[i] - tsiz[i];
            ssz = fmaf(d, d, ssz);
        }
        float smt = 0.0f;
        for (int i = g0; i < BB * NN * 4; i += stride) {
            float d = pmat[i] - tmat[i];
            smt = fmaf(d, d, smt);
        }
        skl = blockReduceSum256(skl); __syncthreads();
        ssz = blockReduceSum256(ssz); __syncthreads();
        smt = blockReduceSum256(smt);
        if (tid == 0) {
            atomicAdd(&ws[1], skl);
            atomicAdd(&ws[2], ssz);
            atomicAdd(&ws[3], smt);
        }
    }
}

// chamfer min-sum: d_min(n) = |p_n|^2 - 2*max_h(n)
__global__ __launch_bounds__(256) void reduce_kernel(
    const float* __restrict__ pred, const float* __restrict__ targ,
    const unsigned* __restrict__ umax, float* __restrict__ ws) {
    const int stride = gridDim.x * blockDim.x;
    float s = 0.0f;
    for (int i = blockIdx.x * blockDim.x + threadIdx.x; i < MAXARR_LEN;
         i += stride) {
        float h = fkeyinv(umax[i]);
        int dir = i >> 15;
        int r = i & 32767;
        int b = r >> 13;
        int n = r & 8191;
        const float* p = (dir ? targ : pred) + ((size_t)b * NN + n) * 3;
        float pp = fmaf(p[0], p[0], fmaf(p[1], p[1], p[2] * p[2]));
        s += pp - 2.0f * h;
    }
    s = blockReduceSum256(s);
    if (threadIdx.x == 0) atomicAdd(&ws[0], s);
}

__global__ void finalize_kernel(const float* __restrict__ ws,
                                float* __restrict__ out) {
    if (threadIdx.x != 0 || blockIdx.x != 0) return;
    float cd = ws[0] / (float)(BB * NN);
    float kl = -0.5f * ws[1] / (float)(BB * LL);
    float sizing = ws[2] / (float)(BB * NN);
    float material = ws[3] / (float)(BB * NN * 4);
    float den = 0.0f;
    for (int b = 0; b < BB; ++b) {
        float s = ws[4 + b], ss = ws[8 + b];
        float var = (ss - s * s / (float)NSUB) / (float)(NSUB - 1);
        den += sqrtf(fmaxf(var, 0.0f));
    }
    den *= (1.0f / BB);
    out[0] = cd + 0.001f * kl + 0.1f * den + 0.05f * sizing + 0.1f * material;
}

extern "C" void kernel_launch(void* const* d_in, const int* in_sizes, int n_in,
                              void* d_out, int out_size, void* d_ws,
                              size_t ws_size, hipStream_t stream) {
    const float* pred_pos = (const float*)d_in[0];
    const float* pred_siz = (const float*)d_in[1];
    const float* pred_mat = (const float*)d_in[2];
    const float* targ_pos = (const float*)d_in[3];
    const float* targ_siz = (const float*)d_in[4];
    const float* targ_mat = (const float*)d_in[5];
    const float* mu = (const float*)d_in[6];
    const float* logvar = (const float*)d_in[7];
    const int* sub_idx = (const int*)d_in[8];
    float* out = (float*)d_out;
    float* ws = (float*)d_ws;
    unsigned* uws = (unsigned*)d_ws;
    unsigned* umax = uws + ACC_N;

    init_ws_kernel<<<64, 256, 0, stream>>>(uws);
    mega_kernel<<<dim3(NCHUNK, NSLICE, 9), 256, 0, stream>>>(
        pred_pos, targ_pos, umax, mu, logvar, pred_siz, targ_siz, pred_mat,
        targ_mat, sub_idx, ws);
    reduce_kernel<<<64, 256, 0, stream>>>(pred_pos, targ_pos, umax, ws);
    finalize_kernel<<<1, 64, 0, stream>>>(ws, out);
}